// Round 21
// baseline (90.081 us; speedup 1.0000x reference)
//
#include <hip/hip_runtime.h>

#define TT 200
#define FF 32
#define HH 50
#define NCH 25      // 25 exact chunks of 8 timesteps (200 = 25*8, no tail)
#define XP 66       // xw col pitch: write banks spread, reads stay 2-way free

typedef _Float16 half8 __attribute__((ext_vector_type(8)));   // 8 f16 = 4 VGPR
typedef __attribute__((ext_vector_type(4))) float f32x4;
typedef __attribute__((ext_vector_type(4))) unsigned int uint32x4;

// tanh(x) = 1 - 2/(exp2(2*log2e*x)+1)
__device__ __forceinline__ float fast_tanh(float x) {
    float e = exp2f(2.885390082f * x);
    return fmaf(-2.0f, __builtin_amdgcn_rcpf(e + 1.0f), 1.0f);
}
__device__ __forceinline__ f32x4 mfmah(half8 a, half8 b, f32x4 c) {
    return __builtin_amdgcn_mfma_f32_16x16x32_f16(a, b, c, 0, 0, 0);
}

// fp16 B-frag of M[kdim x 50] col-slice (RNE). Layout (validated r4-r20):
// lane(r,g) elem e -> B[k=kbase+8g+e][col=c].
__device__ __forceinline__ half8 build_wfrag(const float* __restrict__ M, int kbase,
                                             int kmax, int c, bool cv, int g) {
    unsigned u[4];
#pragma unroll
    for (int q = 0; q < 4; ++q) {
        const int k0 = kbase + 8 * g + 2 * q, k1 = k0 + 1;
        _Float16 v0 = (_Float16)((cv && k0 < kmax) ? M[k0 * HH + c] : 0.0f);
        _Float16 v1 = (_Float16)((cv && k1 < kmax) ? M[k1 * HH + c] : 0.0f);
        u[q] = ((unsigned)__builtin_bit_cast(unsigned short, v1) << 16)
             |  __builtin_bit_cast(unsigned short, v0);
    }
    uint32x4 uu = {u[0], u[1], u[2], u[3]};
    return __builtin_bit_cast(half8, uu);
}

// 8 f32 -> half8 via v_cvt_pkrtz (x-GEMM A path)
__device__ __forceinline__ half8 cvt8(float4 a, float4 b) {
    unsigned u0 = __builtin_bit_cast(unsigned, __builtin_amdgcn_cvt_pkrtz(a.x, a.y));
    unsigned u1 = __builtin_bit_cast(unsigned, __builtin_amdgcn_cvt_pkrtz(a.z, a.w));
    unsigned u2 = __builtin_bit_cast(unsigned, __builtin_amdgcn_cvt_pkrtz(b.x, b.y));
    unsigned u3 = __builtin_bit_cast(unsigned, __builtin_amdgcn_cvt_pkrtz(b.z, b.w));
    uint32x4 uu = {u0, u1, u2, u3};
    return __builtin_bit_cast(half8, uu);
}

// r20 champion shell with 3 waves/SIMD (r20 post-mortem: ~350 cyc/step of
// dependency stall left at 2 waves/SIMD; issue floor at 3 waves ~540 <
// wall 737):
//  - RAGGED grid: 3072 blocks; blocks 0..1023 own 2 rows, 1024..3071 own
//    1 row (slot-duplicated) -> 12 blocks/CU = 3 waves/SIMD.
//  - chunks shortened 16->8 steps (timesteps dup x2 in the chunk GEMM,
//    25 exact chunks): xw 16->8.25 KB so 12 blocks fit LDS (107 KB/CU).
//  - xw col pitch 66: chunk-write banks spread (was the 1.7M conflicts),
//    step reads stay consecutive-64 (2-way, free).
// Same math stream per wave as r16/r20 -> absmax identical.
__global__
__attribute__((amdgpu_flat_work_group_size(64, 64)))
__attribute__((amdgpu_waves_per_eu(3, 4)))
void rnn_fp16(const float* __restrict__ x, const float* __restrict__ W,
              const float* __restrict__ U, const float* __restrict__ b,
              const float* __restrict__ Wd, const float* __restrict__ bd,
              float* __restrict__ out)
{
    __shared__ float xw[2][8][2][XP];     // [chunk parity][t&7][row][col] 8448 B
    __shared__ _Float16 hl[2][2][64];     // [buf][row][col] 512 B

    const int l = threadIdx.x & 63;
    const int r = l & 15;
    const int g = l >> 4;
    const int rl = r & 1;                 // real row (M-dup x8)
    const int bid = blockIdx.x;
    const bool two = (bid < 1024);        // 2-row block?
    const int rb = two ? 2 * bid : bid + 1024;
    const bool gs1 = (g & 1) != 0, gs2 = (g & 2) != 0;
    const int cg = 16 * g + r;            // this lane's h column (0..63)

    half8 Wf[4], U0[4], U1[4];
    f32x4 biasv[4];
#pragma unroll
    for (int n = 0; n < 4; ++n) {
        const int c = 16 * n + r;
        const bool cv = (c < HH);
        Wf[n] = build_wfrag(W, 0,  FF, c, cv, g);
        U0[n] = build_wfrag(U, 0,  HH, c, cv, g);
        U1[n] = build_wfrag(U, 32, HH, c, cv, g);
        const float bv = cv ? b[c] : 0.0f;
        biasv[n] = (f32x4){bv, bv, bv, bv};
    }
    const f32x4 kzero = {0.0f, 0.0f, 0.0f, 0.0f};
    const float wd = (cg < HH) ? Wd[cg] : 0.0f;

    const float* x0 = x + (size_t)(rb + 0) * TT * FF;
    const float* x1 = x + (size_t)(rb + (two ? 1 : 0)) * TT * FF;

    // chunk staging registers (held 8 steps between load and compute);
    // chunk GEMM A-rows: timesteps r&7, dup x2 to fill 16
    float4 r0a, r0b, r1a, r1b;
    auto chunk_load = [&](int cc) {
        int tt = 8 * cc + (r & 7); if (tt > TT - 1) tt = TT - 1;  // clamp cc>=25
        const float* p0 = x0 + (size_t)tt * FF + 8 * g;
        const float* p1 = x1 + (size_t)tt * FF + 8 * g;
        r0a = *(const float4*)p0; r0b = *(const float4*)(p0 + 4);
        r1a = *(const float4*)p1; r1b = *(const float4*)(p1 + 4);
    };
    // xw[t'] = bias + x_t @ W for 8 timesteps (C rows 0..7 real, 8..15 dup)
    auto chunk_compute = [&](int cc) {
        half8 a0 = cvt8(r0a, r0b);
        half8 a1 = cvt8(r1a, r1b);
        const int par = cc & 1;
#pragma unroll
        for (int n = 0; n < 4; ++n) {
            f32x4 c0 = mfmah(a0, Wf[n], biasv[n]);
            f32x4 c1 = mfmah(a1, Wf[n], biasv[n]);
            if (g < 2) {                  // rows 4g+i < 8: the real timesteps
#pragma unroll
                for (int i = 0; i < 4; ++i) {
                    xw[par][4 * g + i][0][16 * n + r] = c0[i];
                    xw[par][4 * g + i][1][16 * n + r] = c1[i];
                }
            }
        }
    };

    // prologue: chunk 0 computed; chunk 1 loads in flight; h buf0 = 0
    chunk_load(0);
    chunk_compute(0);
    chunk_load(1);
    ((unsigned*)hl)[l] = 0u;              // zero both h buffers (512 B)
    ((unsigned*)hl)[64 + l] = 0u;

    float hf0 = 0.0f, hf1 = 0.0f;

    // one step, tl compile-time: immediate LDS offsets, branchless
    auto step_body = [&](int tl, const float* xwp, bool first) {
        const int buf = tl & 1;
        half8 A0, A1;
        if (!first) {
            const _Float16* hp = &hl[buf][rl][0];
            A0 = *(const half8*)(hp + 8 * g);            // k 0..31
            A1 = *(const half8*)(hp + 32 + 8 * g);       // k 32..63 (pad 0)
        }
        f32x4 tot[4];
        if (!first) {
#pragma unroll
            for (int n = 0; n < 4; ++n)   // serial 2-chain, persistent zero C
                tot[n] = mfmah(A1, U1[n], mfmah(A0, U0[n], kzero));
        } else {
#pragma unroll
            for (int n = 0; n < 4; ++n) tot[n] = kzero;
        }
        // select tile g, add xw (immediate-offset b32 reads), tanh, publish
        float m0 = gs2 ? (gs1 ? tot[3][0] : tot[2][0]) : (gs1 ? tot[1][0] : tot[0][0]);
        float m1 = gs2 ? (gs1 ? tot[3][1] : tot[2][1]) : (gs1 ? tot[1][1] : tot[0][1]);
        m0 += xwp[tl * (2 * XP)];         // xw[par][tl][0][cg]
        m1 += xwp[tl * (2 * XP) + XP];    // xw[par][tl][1][cg]
        hf0 = fast_tanh(m0);
        hf1 = fast_tanh(m1);
        hl[buf ^ 1][0][cg] = (_Float16)hf0;   // 2-way banks: free
        hl[buf ^ 1][1][cg] = (_Float16)hf1;
        // no barrier, no waitcnt: wave-private in-order DS
    };

    // 25 exact chunks, 8 steps each, fully unrolled and branchless inside
    for (int c = 0; c < NCH; ++c) {
        const float* xwp = (c & 1) ? &xw[1][0][0][cg] : &xw[0][0][0][cg];
#pragma unroll
        for (int tl = 0; tl < 8; ++tl) {
            step_body(tl, xwp, (c == 0) & (tl == 0));
            if (tl == 4 && c + 1 < NCH) { // compile-time position
                chunk_compute(c + 1);
                chunk_load(c + 2);        // clamps internally for c+2 >= 25
            }
        }
    }

    // head: out[row i] = relu(sum_c h[i][c]*Wd[c] + bd)
    float p0 = hf0 * wd, p1 = hf1 * wd;
#pragma unroll
    for (int m = 1; m <= 32; m <<= 1) {
        p0 += __shfl_xor(p0, m);
        p1 += __shfl_xor(p1, m);
    }
    if (l == 0) {
        const float bdv = bd[0];
        out[rb] = fmaxf(p0 + bdv, 0.0f);
        if (two) out[rb + 1] = fmaxf(p1 + bdv, 0.0f);
    }
}

extern "C" void kernel_launch(void* const* d_in, const int* in_sizes, int n_in,
                              void* d_out, int out_size, void* d_ws, size_t ws_size,
                              hipStream_t stream) {
    const float* x  = (const float*)d_in[0];
    const float* W  = (const float*)d_in[1];
    const float* U  = (const float*)d_in[2];
    const float* b  = (const float*)d_in[3];
    const float* Wd = (const float*)d_in[4];
    const float* bd = (const float*)d_in[5];
    float* out = (float*)d_out;
    // ragged grid: 1024 blocks x 2 rows + 2048 blocks x 1 row = 4096 rows
    dim3 grid(3072), block(64);
    hipLaunchKernelGGL(rnn_fp16, grid, block, 0, stream,
                       x, W, U, b, Wd, bd, out);
    (void)d_ws; (void)ws_size; (void)in_sizes; (void)n_in; (void)out_size;
}

// Round 22
// 63.074 us; speedup vs baseline: 1.4282x; 1.4282x over previous
//
#include <hip/hip_runtime.h>

#define TT 200
#define FF 32
#define HH 50
#define NFULL 12   // 12 full 16-step chunks + 8-step tail (chunk 12)
#define HLP 96     // hl row pitch (f16): h b128 reads hit all 32 banks once

typedef _Float16 half8 __attribute__((ext_vector_type(8)));   // 8 f16 = 4 VGPR
typedef __attribute__((ext_vector_type(4))) float f32x4;
typedef __attribute__((ext_vector_type(2))) float f32x2;
typedef __attribute__((ext_vector_type(4))) unsigned int uint32x4;

// tanh(x) = 1 - 2/(exp2(2*log2e*x)+1)
__device__ __forceinline__ float fast_tanh(float x) {
    float e = exp2f(2.885390082f * x);
    return fmaf(-2.0f, __builtin_amdgcn_rcpf(e + 1.0f), 1.0f);
}
__device__ __forceinline__ f32x4 mfmah(half8 a, half8 b, f32x4 c) {
    return __builtin_amdgcn_mfma_f32_16x16x32_f16(a, b, c, 0, 0, 0);
}

// fp16 B-frag of M[kdim x 50] col-slice (RNE). Layout (validated r4-r21):
// lane(r,g) elem e -> B[k=kbase+8g+e][col=c].
__device__ __forceinline__ half8 build_wfrag(const float* __restrict__ M, int kbase,
                                             int kmax, int c, bool cv, int g) {
    unsigned u[4];
#pragma unroll
    for (int q = 0; q < 4; ++q) {
        const int k0 = kbase + 8 * g + 2 * q, k1 = k0 + 1;
        _Float16 v0 = (_Float16)((cv && k0 < kmax) ? M[k0 * HH + c] : 0.0f);
        _Float16 v1 = (_Float16)((cv && k1 < kmax) ? M[k1 * HH + c] : 0.0f);
        u[q] = ((unsigned)__builtin_bit_cast(unsigned short, v1) << 16)
             |  __builtin_bit_cast(unsigned short, v0);
    }
    uint32x4 uu = {u[0], u[1], u[2], u[3]};
    return __builtin_bit_cast(half8, uu);
}

// 8 f32 -> half8 via v_cvt_pkrtz (x-GEMM A path)
__device__ __forceinline__ half8 cvt8(float4 a, float4 b) {
    unsigned u0 = __builtin_bit_cast(unsigned, __builtin_amdgcn_cvt_pkrtz(a.x, a.y));
    unsigned u1 = __builtin_bit_cast(unsigned, __builtin_amdgcn_cvt_pkrtz(a.z, a.w));
    unsigned u2 = __builtin_bit_cast(unsigned, __builtin_amdgcn_cvt_pkrtz(b.x, b.y));
    unsigned u3 = __builtin_bit_cast(unsigned, __builtin_amdgcn_cvt_pkrtz(b.z, b.w));
    uint32x4 uu = {u0, u1, u2, u3};
    return __builtin_bit_cast(half8, uu);
}

// r20 champion shell (1 wave/block, 2 real rows M-dup x8, 2048 blocks =
// 2 phase-independent waves/SIMD, 16-step chunk x-GEMM, barrier/waitcnt-
// free wave-private recurrence, fully-unrolled branchless chunks) + 3
// micro-cuts (r21 falsified more-TLP: wall = 2 x per-wave-issue; lever
// is ISSUE and LDS-pipe per wave):
//  1. xw packed [t'][col][row0,row1]: 1 ds_read_b64/step (was 2 b32),
//     16 ds_write_b64/chunk (was 32 b32) — same bytes, half the slots.
//  2. hl pitch 96 f16: h b128 read banks rl*16+4g+{0..3} = all 32 banks
//     exactly once — kills r20's 1.7M conflicts.
//  3. chunk burst spread over tl=4..10 (cvt / tile GEMM+store x4 / loads)
//     so the co-wave never sees a monolithic MFMA+store burst.
__global__
__attribute__((amdgpu_flat_work_group_size(64, 64)))
__attribute__((amdgpu_waves_per_eu(2, 2)))
void rnn_fp16(const float* __restrict__ x, const float* __restrict__ W,
              const float* __restrict__ U, const float* __restrict__ b,
              const float* __restrict__ Wd, const float* __restrict__ bd,
              float* __restrict__ out)
{
    __shared__ f32x2 xw[2][16][66];       // [parity][t'][col(+pad)] row-pairs
    __shared__ _Float16 hl[2][2][HLP];    // [buf][row][col] padded pitch

    const int l = threadIdx.x & 63;
    const int r = l & 15;
    const int g = l >> 4;
    const int rl = r & 1;                 // real row (M-dup x8)
    const int rb = blockIdx.x * 2;
    const bool gs1 = (g & 1) != 0, gs2 = (g & 2) != 0;
    const int cg = 16 * g + r;            // this lane's h column (0..63)

    half8 Wf[4], U0[4], U1[4];
    f32x4 biasv[4];
#pragma unroll
    for (int n = 0; n < 4; ++n) {
        const int c = 16 * n + r;
        const bool cv = (c < HH);
        Wf[n] = build_wfrag(W, 0,  FF, c, cv, g);
        U0[n] = build_wfrag(U, 0,  HH, c, cv, g);
        U1[n] = build_wfrag(U, 32, HH, c, cv, g);
        const float bv = cv ? b[c] : 0.0f;
        biasv[n] = (f32x4){bv, bv, bv, bv};
    }
    const f32x4 kzero = {0.0f, 0.0f, 0.0f, 0.0f};
    const float wd = (cg < HH) ? Wd[cg] : 0.0f;

    const float* x0 = x + (size_t)(rb + 0) * TT * FF;
    const float* x1 = x + (size_t)(rb + 1) * TT * FF;

    // chunk staging regs (held ~16 steps between load and compute)
    float4 r0a, r0b, r1a, r1b;
    half8 ca0, ca1;                       // cvt'd A-frags (made at tl==4)
    auto chunk_load = [&](int cc) {
        int tt = 16 * cc + r; if (tt > TT - 1) tt = TT - 1;   // clamp cc>12
        const float* p0 = x0 + (size_t)tt * FF + 8 * g;
        const float* p1 = x1 + (size_t)tt * FF + 8 * g;
        r0a = *(const float4*)p0; r0b = *(const float4*)(p0 + 4);
        r1a = *(const float4*)p1; r1b = *(const float4*)(p1 + 4);
    };
    // one tile of the 16-timestep x-GEMM; stores row-pairs as b64
    auto chunk_tile = [&](int par, int n) {
        f32x4 c0 = mfmah(ca0, Wf[n], biasv[n]);
        f32x4 c1 = mfmah(ca1, Wf[n], biasv[n]);
#pragma unroll
        for (int i = 0; i < 4; ++i)
            xw[par][4 * g + i][16 * n + r] = (f32x2){c0[i], c1[i]};
    };

    // prologue: chunk 0 computed; chunk 1 loads in flight; h buf0 = 0
    chunk_load(0);
    ca0 = cvt8(r0a, r0b); ca1 = cvt8(r1a, r1b);
    chunk_tile(0, 0); chunk_tile(0, 1); chunk_tile(0, 2); chunk_tile(0, 3);
    chunk_load(1);
    hl[0][0][cg] = (_Float16)0.0f;
    hl[0][1][cg] = (_Float16)0.0f;

    float hf0 = 0.0f, hf1 = 0.0f;

    // one step, tl compile-time: immediate LDS offsets, branchless
    auto step_body = [&](int tl, const f32x2* xwp, bool first) {
        const int buf = tl & 1;
        half8 A0, A1;
        if (!first) {
            const _Float16* hp = &hl[buf][rl][0];
            A0 = *(const half8*)(hp + 8 * g);            // k 0..31
            A1 = *(const half8*)(hp + 32 + 8 * g);       // k 32..63 (pad 0)
        }
        f32x4 tot[4];
        if (!first) {
#pragma unroll
            for (int n = 0; n < 4; ++n)   // serial 2-chain, persistent zero C
                tot[n] = mfmah(A1, U1[n], mfmah(A0, U0[n], kzero));
        } else {
#pragma unroll
            for (int n = 0; n < 4; ++n) tot[n] = kzero;
        }
        // select tile g, add xw row-pair (ONE b64 read), tanh, publish
        float m0 = gs2 ? (gs1 ? tot[3][0] : tot[2][0]) : (gs1 ? tot[1][0] : tot[0][0]);
        float m1 = gs2 ? (gs1 ? tot[3][1] : tot[2][1]) : (gs1 ? tot[1][1] : tot[0][1]);
        const f32x2 xv = xwp[tl * 66];    // xw[par][tl][cg]
        m0 += xv[0];
        m1 += xv[1];
        hf0 = fast_tanh(m0);
        hf1 = fast_tanh(m1);
        hl[buf ^ 1][0][cg] = (_Float16)hf0;
        hl[buf ^ 1][1][cg] = (_Float16)hf1;
        // no barrier, no waitcnt: wave-private in-order DS
    };

    // 12 full chunks, 16 steps each, fully unrolled; chunk work spread
    for (int c = 0; c < NFULL; ++c) {
        const f32x2* xwp = (c & 1) ? &xw[1][0][cg] : &xw[0][0][cg];
        const int npar = (c + 1) & 1;
#pragma unroll
        for (int tl = 0; tl < 16; ++tl) {
            step_body(tl, xwp, (c == 0) & (tl == 0));
            // spread next-chunk work: cvt @4, tiles @5-8, loads @10
            if (tl == 4) { ca0 = cvt8(r0a, r0b); ca1 = cvt8(r1a, r1b); }
            if (tl == 5) chunk_tile(npar, 0);
            if (tl == 6) chunk_tile(npar, 1);
            if (tl == 7) chunk_tile(npar, 2);
            if (tl == 8) chunk_tile(npar, 3);
            if (tl == 10) chunk_load(c + 2);   // clamps internally for c+2 > 12
        }
    }
    // tail: chunk 12 (parity 0), steps t = 192..199
    {
        const f32x2* xwp = &xw[0][0][cg];
#pragma unroll
        for (int tl = 0; tl < 8; ++tl) step_body(tl, xwp, false);
    }

    // head: out[row i] = relu(sum_c h[i][c]*Wd[c] + bd)
    float p0 = hf0 * wd, p1 = hf1 * wd;
#pragma unroll
    for (int m = 1; m <= 32; m <<= 1) {
        p0 += __shfl_xor(p0, m);
        p1 += __shfl_xor(p1, m);
    }
    if (l == 0) {
        const float bdv = bd[0];
        out[rb + 0] = fmaxf(p0 + bdv, 0.0f);
        out[rb + 1] = fmaxf(p1 + bdv, 0.0f);
    }
}

extern "C" void kernel_launch(void* const* d_in, const int* in_sizes, int n_in,
                              void* d_out, int out_size, void* d_ws, size_t ws_size,
                              hipStream_t stream) {
    const float* x  = (const float*)d_in[0];
    const float* W  = (const float*)d_in[1];
    const float* U  = (const float*)d_in[2];
    const float* b  = (const float*)d_in[3];
    const float* Wd = (const float*)d_in[4];
    const float* bd = (const float*)d_in[5];
    float* out = (float*)d_out;
    const int B = out_size;                       // 4096
    dim3 grid(B / 2), block(64);                  // 2048 blocks, 1 wave, 2 rows
    hipLaunchKernelGGL(rnn_fp16, grid, block, 0, stream,
                       x, W, U, b, Wd, bd, out);
    (void)d_ws; (void)ws_size; (void)in_sizes; (void)n_in;
}

// Round 23
// 61.976 us; speedup vs baseline: 1.4535x; 1.0177x over previous
//
#include <hip/hip_runtime.h>

#define TT 200
#define FF 32
#define HH 50
#define NFULL 12   // 12 full 16-step chunks + 8-step tail (chunk 12)

typedef _Float16 half8 __attribute__((ext_vector_type(8)));   // 8 f16 = 4 VGPR
typedef __attribute__((ext_vector_type(4))) float f32x4;
typedef __attribute__((ext_vector_type(4))) unsigned int uint32x4;

// tanh(x) = 1 - 2/(exp2(2*log2e*x)+1)
__device__ __forceinline__ float fast_tanh(float x) {
    float e = exp2f(2.885390082f * x);
    return fmaf(-2.0f, __builtin_amdgcn_rcpf(e + 1.0f), 1.0f);
}
__device__ __forceinline__ f32x4 mfmah(half8 a, half8 b, f32x4 c) {
    return __builtin_amdgcn_mfma_f32_16x16x32_f16(a, b, c, 0, 0, 0);
}

// fp16 B-frag of M[kdim x 50] col-slice (RNE). Layout (validated r4-r22):
// lane(r,g) elem e -> B[k=kbase+8g+e][col=c].
__device__ __forceinline__ half8 build_wfrag(const float* __restrict__ M, int kbase,
                                             int kmax, int c, bool cv, int g) {
    unsigned u[4];
#pragma unroll
    for (int q = 0; q < 4; ++q) {
        const int k0 = kbase + 8 * g + 2 * q, k1 = k0 + 1;
        _Float16 v0 = (_Float16)((cv && k0 < kmax) ? M[k0 * HH + c] : 0.0f);
        _Float16 v1 = (_Float16)((cv && k1 < kmax) ? M[k1 * HH + c] : 0.0f);
        u[q] = ((unsigned)__builtin_bit_cast(unsigned short, v1) << 16)
             |  __builtin_bit_cast(unsigned short, v0);
    }
    uint32x4 uu = {u[0], u[1], u[2], u[3]};
    return __builtin_bit_cast(half8, uu);
}

// 8 f32 -> half8 via v_cvt_pkrtz (x-GEMM A path)
__device__ __forceinline__ half8 cvt8(float4 a, float4 b) {
    unsigned u0 = __builtin_bit_cast(unsigned, __builtin_amdgcn_cvt_pkrtz(a.x, a.y));
    unsigned u1 = __builtin_bit_cast(unsigned, __builtin_amdgcn_cvt_pkrtz(a.z, a.w));
    unsigned u2 = __builtin_bit_cast(unsigned, __builtin_amdgcn_cvt_pkrtz(b.x, b.y));
    unsigned u3 = __builtin_bit_cast(unsigned, __builtin_amdgcn_cvt_pkrtz(b.z, b.w));
    uint32x4 uu = {u0, u1, u2, u3};
    return __builtin_bit_cast(half8, uu);
}

// CHAMPION (r20, 61.4 us): 1 wave/block, 2 real rows M-dup x8, 2048 blocks
// = 2 phase-independent waves/SIMD, chunk-batched x-GEMM staged in LDS f32,
// f16 h in LDS, barrier/waitcnt-free wave-private recurrence, 12 fully-
// unrolled branchless 16-step chunks + 8-step tail.
// Design-space bracketing (r8/r9/r14/r15/r18/r19/r21/r22): more TLP +47%,
// less dup +39-105%, barrier >=25% worse, register-crossbar +31%, fused-x
// +25%, conflict/slot micro-opts neutral. wall = 2 x ~368 cyc/wave-step
// (8 MFMA + ~120 VALU/trans + LDS + ~100 unhidden dep) is the practical
// floor of this family for a 200-step serial recurrence on 4096 rows.
__global__
__attribute__((amdgpu_flat_work_group_size(64, 64)))
__attribute__((amdgpu_waves_per_eu(2, 2)))
void rnn_fp16(const float* __restrict__ x, const float* __restrict__ W,
              const float* __restrict__ U, const float* __restrict__ b,
              const float* __restrict__ Wd, const float* __restrict__ bd,
              float* __restrict__ out)
{
    __shared__ float xw[2][16][2][64];    // [chunk parity][t&15][row][col] 16 KB
    __shared__ _Float16 hl[2][2][64];     // [buf][row][col] 512 B

    const int l = threadIdx.x & 63;
    const int r = l & 15;
    const int g = l >> 4;
    const int rl = r & 1;                 // real row (M-dup x8)
    const int rb = blockIdx.x * 2;
    const bool gs1 = (g & 1) != 0, gs2 = (g & 2) != 0;
    const int cg = 16 * g + r;            // this lane's h column (0..63)

    half8 Wf[4], U0[4], U1[4];
    f32x4 biasv[4];
#pragma unroll
    for (int n = 0; n < 4; ++n) {
        const int c = 16 * n + r;
        const bool cv = (c < HH);
        Wf[n] = build_wfrag(W, 0,  FF, c, cv, g);
        U0[n] = build_wfrag(U, 0,  HH, c, cv, g);
        U1[n] = build_wfrag(U, 32, HH, c, cv, g);
        const float bv = cv ? b[c] : 0.0f;
        biasv[n] = (f32x4){bv, bv, bv, bv};
    }
    const f32x4 kzero = {0.0f, 0.0f, 0.0f, 0.0f};
    const float wd = (cg < HH) ? Wd[cg] : 0.0f;

    const float* x0 = x + (size_t)(rb + 0) * TT * FF;
    const float* x1 = x + (size_t)(rb + 1) * TT * FF;

    // chunk staging registers (held 16 steps between load and compute)
    float4 r0a, r0b, r1a, r1b;
    auto chunk_load = [&](int cc) {
        int tt = 16 * cc + r; if (tt > TT - 1) tt = TT - 1;   // clamp: safe for cc>12
        const float* p0 = x0 + (size_t)tt * FF + 8 * g;
        const float* p1 = x1 + (size_t)tt * FF + 8 * g;
        r0a = *(const float4*)p0; r0b = *(const float4*)(p0 + 4);
        r1a = *(const float4*)p1; r1b = *(const float4*)(p1 + 4);
    };
    // xw[t] = bias + x_t @ W for 16 timesteps (M = timesteps GEMM) -> LDS f32
    auto chunk_compute = [&](int cc) {
        half8 a0 = cvt8(r0a, r0b);
        half8 a1 = cvt8(r1a, r1b);
        const int par = cc & 1;
#pragma unroll
        for (int n = 0; n < 4; ++n) {
            f32x4 c0 = mfmah(a0, Wf[n], biasv[n]);
            f32x4 c1 = mfmah(a1, Wf[n], biasv[n]);
#pragma unroll
            for (int i = 0; i < 4; ++i) {
                xw[par][4 * g + i][0][16 * n + r] = c0[i];
                xw[par][4 * g + i][1][16 * n + r] = c1[i];
            }
        }
    };

    // prologue: chunk 0 computed; chunk 1 loads in flight; h buf0 = 0
    chunk_load(0);
    chunk_compute(0);
    chunk_load(1);
    ((unsigned*)hl)[l] = 0u;              // zero both h buffers (512 B)
    ((unsigned*)hl)[64 + l] = 0u;

    float hf0 = 0.0f, hf1 = 0.0f;

    // one step, tl compile-time: immediate LDS offsets, branchless
    auto step_body = [&](int tl, const float* xwp, bool first) {
        const int buf = tl & 1;
        half8 A0, A1;
        if (!first) {
            const _Float16* hp = &hl[buf][rl][0];
            A0 = *(const half8*)(hp + 8 * g);            // k 0..31
            A1 = *(const half8*)(hp + 32 + 8 * g);       // k 32..63 (pad 0)
        }
        f32x4 tot[4];
        if (!first) {
#pragma unroll
            for (int n = 0; n < 4; ++n)   // serial 2-chain, persistent zero C
                tot[n] = mfmah(A1, U1[n], mfmah(A0, U0[n], kzero));
        } else {
#pragma unroll
            for (int n = 0; n < 4; ++n) tot[n] = kzero;
        }
        // select tile g, add xw (immediate-offset b32 reads), tanh, publish
        float m0 = gs2 ? (gs1 ? tot[3][0] : tot[2][0]) : (gs1 ? tot[1][0] : tot[0][0]);
        float m1 = gs2 ? (gs1 ? tot[3][1] : tot[2][1]) : (gs1 ? tot[1][1] : tot[0][1]);
        m0 += xwp[tl * 128];              // xw[par][tl][0][cg]
        m1 += xwp[tl * 128 + 64];         // xw[par][tl][1][cg]
        hf0 = fast_tanh(m0);
        hf1 = fast_tanh(m1);
        hl[buf ^ 1][0][cg] = (_Float16)hf0;   // 2-way banks: free
        hl[buf ^ 1][1][cg] = (_Float16)hf1;
        // no barrier, no waitcnt: wave-private in-order DS
    };

    // 12 full chunks, 16 steps each, fully unrolled and branchless
    for (int c = 0; c < NFULL; ++c) {
        const float* xwp = (c & 1) ? &xw[1][0][0][cg] : &xw[0][0][0][cg];
#pragma unroll
        for (int tl = 0; tl < 16; ++tl) {
            step_body(tl, xwp, (c == 0) & (tl == 0));
            if (tl == 8) {                // compile-time position, no branch
                chunk_compute(c + 1);     // c+1 <= 12: always valid
                chunk_load(c + 2);        // c+2 == 13 clamps harmlessly
            }
        }
    }
    // tail: chunk 12 (parity 0), steps t = 192..199, no prefetch machinery
    {
        const float* xwp = &xw[0][0][0][cg];
#pragma unroll
        for (int tl = 0; tl < 8; ++tl) step_body(tl, xwp, false);
    }

    // head: out[row i] = relu(sum_c h[i][c]*Wd[c] + bd)
    float p0 = hf0 * wd, p1 = hf1 * wd;
#pragma unroll
    for (int m = 1; m <= 32; m <<= 1) {
        p0 += __shfl_xor(p0, m);
        p1 += __shfl_xor(p1, m);
    }
    if (l == 0) {
        const float bdv = bd[0];
        out[rb + 0] = fmaxf(p0 + bdv, 0.0f);
        out[rb + 1] = fmaxf(p1 + bdv, 0.0f);
    }
}

extern "C" void kernel_launch(void* const* d_in, const int* in_sizes, int n_in,
                              void* d_out, int out_size, void* d_ws, size_t ws_size,
                              hipStream_t stream) {
    const float* x  = (const float*)d_in[0];
    const float* W  = (const float*)d_in[1];
    const float* U  = (const float*)d_in[2];
    const float* b  = (const float*)d_in[3];
    const float* Wd = (const float*)d_in[4];
    const float* bd = (const float*)d_in[5];
    float* out = (float*)d_out;
    const int B = out_size;                       // 4096
    dim3 grid(B / 2), block(64);                  // 2048 blocks, 1 wave, 2 rows
    hipLaunchKernelGGL(rnn_fp16, grid, block, 0, stream,
                       x, W, U, b, Wd, bd, out);
    (void)d_ws; (void)ws_size; (void)in_sizes; (void)n_in;
}